// Round 9
// baseline (66.012 us; speedup 1.0000x reference)
//
#include <hip/hip_runtime.h>
#include <math.h>

#define NBINS 513
#define NROWS 4000
#define BATCH 8
#define FPW   8                          // output rows per chain
#define CHAINS_PER_BATCH (NROWS / FPW)   // 500 (2 chains per wave -> 250 blocks)

__device__ __forceinline__ void cmul(float& ar, float& ai, float br, float bi) {
    const float t = ar * br - ai * bi;
    ai = ar * bi + ai * br;
    ar = t;
}

// In-place inverse DFT-8 (omega = e^{+2pi i/8}) on 8 complex register values.
__device__ __forceinline__ void idft8(float* xr, float* xi) {
    const float S = 0.70710678118654752440f;
    float er[4], ei[4], orr[4], oi[4];
    #pragma unroll
    for (int j = 0; j < 4; ++j) {
        er[j]  = xr[j] + xr[j+4];  ei[j] = xi[j] + xi[j+4];
        orr[j] = xr[j] - xr[j+4];  oi[j] = xi[j] - xi[j+4];
    }
    const float f1r = S * (orr[1] - oi[1]), f1i = S * (orr[1] + oi[1]);
    const float f2r = -oi[2],               f2i = orr[2];
    const float f3r = S * (-orr[3] - oi[3]), f3i = S * (orr[3] - oi[3]);
    {   // DFT4 (w4 = +i) over evens -> y0,y2,y4,y6
        const float eer = er[0]+er[2], eei = ei[0]+ei[2];
        const float eor = er[0]-er[2], eoi = ei[0]-ei[2];
        const float oer = er[1]+er[3], oei = ei[1]+ei[3];
        const float oor = er[1]-er[3], ooi = ei[1]-ei[3];
        xr[0] = eer + oer;  xi[0] = eei + oei;
        xr[2] = eor - ooi;  xi[2] = eoi + oor;
        xr[4] = eer - oer;  xi[4] = eei - oei;
        xr[6] = eor + ooi;  xi[6] = eoi - oor;
    }
    {   // DFT4 over odds*w8 -> y1,y3,y5,y7
        const float eer = orr[0]+f2r, eei = oi[0]+f2i;
        const float eor = orr[0]-f2r, eoi = oi[0]-f2i;
        const float oer = f1r+f3r,    oei = f1i+f3i;
        const float oor = f1r-f3r,    ooi = f1i-f3i;
        xr[1] = eer + oer;  xi[1] = eei + oei;
        xr[3] = eor - ooi;  xi[3] = eoi + oor;
        xr[5] = eer - oer;  xi[5] = eei - oei;
        xr[7] = eor + ooi;  xi[7] = eoi - oor;
    }
}

__global__ __launch_bounds__(64) void istft_kernel(
    const float* __restrict__ re, const float* __restrict__ im,
    float* __restrict__ out)
{
    __shared__ float4 ex4[512];        // wave-private exchange: {reA,imA,reB,imB}

    const int u   = threadIdx.x;       // 0..63
    const int b   = blockIdx.y;
    const int t0A = (blockIdx.x * 2)     * FPW;
    const int t0B = (blockIdx.x * 2 + 1) * FPW;

    const int k1 = u >> 3;
    const int k2 = u & 7;

    // ---- per-thread twiddles ----
    const float w0 = 6.283185307179586476925f / 1024.0f;
    const float F  = 4.8828125e-4f;    // 0.5 (harness) * packed-irfft norm

    float2 twn[8];                     // F * i * w1024^(u+64j)  (pack rotation)
    #pragma unroll
    for (int j = 0; j < 8; ++j) {
        float s, c; sincosf(w0 * (float)(u + 64 * j), &s, &c);
        twn[j] = make_float2(-F * s, F * c);
    }
    float2 wA, wB0, wBs;               // stage twiddle recurrence bases
    {
        float s, c;
        sincosf(w0 * (float)(16 * k1), &s, &c);     wA  = make_float2(c, s);
        sincosf(w0 * (float)(2 * k2 * k1), &s, &c); wB0 = make_float2(c, s);
        sincosf(w0 * (float)(16 * k2), &s, &c);     wBs = make_float2(c, s);
    }

    float2 cc[2][4];                   // OLA carries, both chains
    #pragma unroll
    for (int q = 0; q < 2; ++q)
        #pragma unroll
        for (int m = 0; m < 4; ++m) cc[q][m] = make_float2(0.f, 0.f);

    const float* rebase = re + (size_t)b * NROWS * NBINS;
    const float* imbase = im + (size_t)b * NROWS * NBINS;

    // ---- prefetch registers: raw inputs of the NEXT frame, both chains ----
    float pxr[2][8], pxi[2][8], pmr[2][8], pmi[2][8];

    auto issue_loads = [&](int it) {
        #pragma unroll
        for (int q = 0; q < 2; ++q) {
            const int t = (q ? t0B : t0A) - 1 + it;
            if (t >= 0) {              // uniform branch (only block 0 chain A @ it=0)
                const float* rp = rebase + (size_t)t * NBINS;
                const float* ip = imbase + (size_t)t * NBINS;
                #pragma unroll
                for (int j = 0; j < 8; ++j) {
                    const int k = u + 64 * j;
                    pxr[q][j] = rp[k];        pxi[q][j] = ip[k];
                    pmr[q][j] = rp[512 - k];  pmi[q][j] = ip[512 - k];  // k=0 -> bin 512
                }
            } else {
                #pragma unroll
                for (int j = 0; j < 8; ++j) {
                    pxr[q][j]=0.f; pxi[q][j]=0.f; pmr[q][j]=0.f; pmi[q][j]=0.f;
                }
            }
        }
    };

    issue_loads(0);                    // priming frames

    for (int it = 0; it <= FPW; ++it) {
        // ---- pack both chains: z = F*e + twn*h ----
        float zr[2][8], zi[2][8];
        #pragma unroll
        for (int q = 0; q < 2; ++q) {
            #pragma unroll
            for (int j = 0; j < 8; ++j) {
                const int k = u + 64 * j;
                float xr = pxr[q][j], xi = pxi[q][j];
                float rc = pmr[q][j], ic = -pmi[q][j];
                if (k == 0) { xi = 0.f; ic = 0.f; }   // pocketfft c2r: Im ignored
                const float er0 = xr + rc, ei0 = xi + ic;
                const float hr0 = xr - rc, hi0 = xi - ic;
                zr[q][j] = F * er0 + (twn[j].x * hr0 - twn[j].y * hi0);
                zi[q][j] = F * ei0 + (twn[j].x * hi0 + twn[j].y * hr0);
            }
        }

        // ---- issue next frames' loads; latency hides under the FFTs ----
        if (it < FPW) issue_loads(it + 1);

        // ---- stage A (both chains), shared twiddle recurrence ----
        idft8(zr[0], zi[0]);
        idft8(zr[1], zi[1]);
        {
            float tr = wA.x, ti = wA.y;
            #pragma unroll
            for (int m0 = 1; m0 < 8; ++m0) {
                cmul(zr[0][m0], zi[0][m0], tr, ti);
                cmul(zr[1][m0], zi[1][m0], tr, ti);
                cmul(tr, ti, wA.x, wA.y);
            }
        }
        // ---- exchange 1 (wave-internal, XOR swizzle, b128 payload) ----
        #pragma unroll
        for (int m0 = 0; m0 < 8; ++m0)
            ex4[64 * m0 + 8 * ((k1 ^ m0) & 7) + k2] =
                make_float4(zr[0][m0], zi[0][m0], zr[1][m0], zi[1][m0]);
        #pragma unroll
        for (int kk = 0; kk < 8; ++kk) {
            const float4 v = ex4[64 * k1 + 8 * ((kk ^ k1) & 7) + k2];
            zr[0][kk] = v.x; zi[0][kk] = v.y; zr[1][kk] = v.z; zi[1][kk] = v.w;
        }

        // ---- stage B (both chains), shared recurrence ----
        idft8(zr[0], zi[0]);
        idft8(zr[1], zi[1]);
        {
            float tr = wB0.x, ti = wB0.y;
            #pragma unroll
            for (int m1 = 0; m1 < 8; ++m1) {
                cmul(zr[0][m1], zi[0][m1], tr, ti);
                cmul(zr[1][m1], zi[1][m1], tr, ti);
                cmul(tr, ti, wBs.x, wBs.y);
            }
        }
        // ---- exchange 2 ----
        #pragma unroll
        for (int m1 = 0; m1 < 8; ++m1)
            ex4[64 * k2 + 8 * ((m1 ^ k2) & 7) + k1] =
                make_float4(zr[0][m1], zi[0][m1], zr[1][m1], zi[1][m1]);
        #pragma unroll
        for (int kk = 0; kk < 8; ++kk) {
            const float4 v = ex4[64 * kk + 8 * ((k1 ^ kk) & 7) + k2];
            zr[0][kk] = v.x; zi[0][kk] = v.y; zr[1][kk] = v.z; zi[1][kk] = v.w;
        }

        // ---- stage C (both chains) -> z[u + 64*m2] ----
        idft8(zr[0], zi[0]);
        idft8(zr[1], zi[1]);

        // ---- overlap-add, carries in registers ----
        if (it >= 1) {
            #pragma unroll
            for (int q = 0; q < 2; ++q) {
                const int t = (q ? t0B : t0A) - 1 + it;
                float2* orow = (float2*)(out + ((size_t)b * NROWS + (size_t)t) * 512);
                #pragma unroll
                for (int m = 0; m < 4; ++m)
                    orow[u + 64 * m] =
                        make_float2(zr[q][m] + cc[q][m].x, zi[q][m] + cc[q][m].y);
            }
        }
        #pragma unroll
        for (int q = 0; q < 2; ++q)
            #pragma unroll
            for (int m = 0; m < 4; ++m)
                cc[q][m] = make_float2(zr[q][m + 4], zi[q][m + 4]);
    }
}

extern "C" void kernel_launch(void* const* d_in, const int* in_sizes, int n_in,
                              void* d_out, int out_size, void* d_ws, size_t ws_size,
                              hipStream_t stream) {
    const float* re = (const float*)d_in[0];
    const float* im = (const float*)d_in[1];
    float* out = (float*)d_out;
    dim3 grid(CHAINS_PER_BATCH / 2, BATCH);
    istft_kernel<<<grid, 64, 0, stream>>>(re, im, out);
}

// Round 11
// 43.757 us; speedup vs baseline: 1.5086x; 1.5086x over previous
//
#include <hip/hip_runtime.h>
#include <math.h>

#define NBINS 513
#define NROWS 4000
#define BATCH 8
#define FPW   8                          // output rows per chain (1 wave = 1 chain)
#define CHAINS_PER_BATCH (NROWS / FPW)   // 500

typedef const __attribute__((address_space(1))) void* gvp;
typedef __attribute__((address_space(3))) void* lvp;

__device__ __forceinline__ void cmul(float& ar, float& ai, float br, float bi) {
    const float t = ar * br - ai * bi;
    ai = ar * bi + ai * br;
    ar = t;
}

// In-place inverse DFT-8 (omega = e^{+2pi i/8}) on 8 complex register values.
__device__ __forceinline__ void idft8(float* xr, float* xi) {
    const float S = 0.70710678118654752440f;
    float er[4], ei[4], orr[4], oi[4];
    #pragma unroll
    for (int j = 0; j < 4; ++j) {
        er[j]  = xr[j] + xr[j+4];  ei[j] = xi[j] + xi[j+4];
        orr[j] = xr[j] - xr[j+4];  oi[j] = xi[j] - xi[j+4];
    }
    const float f1r = S * (orr[1] - oi[1]), f1i = S * (orr[1] + oi[1]);
    const float f2r = -oi[2],               f2i = orr[2];
    const float f3r = S * (-orr[3] - oi[3]), f3i = S * (orr[3] - oi[3]);
    {   // DFT4 (w4 = +i) over evens -> y0,y2,y4,y6
        const float eer = er[0]+er[2], eei = ei[0]+ei[2];
        const float eor = er[0]-er[2], eoi = ei[0]-ei[2];
        const float oer = er[1]+er[3], oei = ei[1]+ei[3];
        const float oor = er[1]-er[3], ooi = ei[1]-ei[3];
        xr[0] = eer + oer;  xi[0] = eei + oei;
        xr[2] = eor - ooi;  xi[2] = eoi + oor;
        xr[4] = eer - oer;  xi[4] = eei - oei;
        xr[6] = eor + ooi;  xi[6] = eoi - oor;
    }
    {   // DFT4 over odds*w8 -> y1,y3,y5,y7
        const float eer = orr[0]+f2r, eei = oi[0]+f2i;
        const float eor = orr[0]-f2r, eoi = oi[0]-f2i;
        const float oer = f1r+f3r,    oei = f1i+f3i;
        const float oor = f1r-f3r,    ooi = f1i-f3i;
        xr[1] = eer + oer;  xi[1] = eei + oei;
        xr[3] = eor - ooi;  xi[3] = eoi + oor;
        xr[5] = eer - oer;  xi[5] = eei - oei;
        xr[7] = eor + ooi;  xi[7] = eoi - oor;
    }
}

__global__ __launch_bounds__(64) void istft_kernel(
    const float* __restrict__ re, const float* __restrict__ im,
    float* __restrict__ out)
{
    __shared__ float  st[2][2][516];   // [buf][re/im][bin 0..512] staging
    __shared__ float2 ex2[512];        // exchange region

    const int u  = threadIdx.x;        // 0..63
    const int b  = blockIdx.y;
    const int t0 = blockIdx.x * FPW;

    const int k1 = u >> 3;
    const int k2 = u & 7;

    // ---- per-thread twiddles (registers) ----
    const float w0 = 6.283185307179586476925f / 1024.0f;
    const float F  = 4.8828125e-4f;    // 0.5 (harness) * packed-irfft norm

    float2 twn[8];                     // F * i * w1024^(u+64j)  (pack rotation)
    #pragma unroll
    for (int j = 0; j < 8; ++j) {
        float s, c; sincosf(w0 * (float)(u + 64 * j), &s, &c);
        twn[j] = make_float2(-F * s, F * c);
    }
    float2 wA, wB0, wBs;               // stage twiddle recurrence bases
    {
        float s, c;
        sincosf(w0 * (float)(16 * k1), &s, &c);     wA  = make_float2(c, s);
        sincosf(w0 * (float)(2 * k2 * k1), &s, &c); wB0 = make_float2(c, s);
        sincosf(w0 * (float)(16 * k2), &s, &c);     wBs = make_float2(c, s);
    }

    float2 cc[4];                      // OLA carry (registers)
    #pragma unroll
    for (int m = 0; m < 4; ++m) cc[m] = make_float2(0.f, 0.f);

    const float* rebase = re + (size_t)b * NROWS * NBINS;
    const float* imbase = im + (size_t)b * NROWS * NBINS;

    // ---- async staging of one spectrum row into LDS (size=4: alignment-safe,
    //      offset=0 everywhere: no untested immediate-offset semantics) ----
    auto stage = [&](int t, int buf) {
        const float* rp = rebase + (size_t)t * NBINS;
        const float* ip = imbase + (size_t)t * NBINS;
        #pragma unroll
        for (int jj = 0; jj < 8; ++jj)
            __builtin_amdgcn_global_load_lds((gvp)(rp + 64 * jj + u),
                                             (lvp)&st[buf][0][64 * jj], 4, 0, 0);
        __builtin_amdgcn_global_load_lds((gvp)(rp + 449 + u),
                                         (lvp)&st[buf][0][449], 4, 0, 0);
        #pragma unroll
        for (int jj = 0; jj < 8; ++jj)
            __builtin_amdgcn_global_load_lds((gvp)(ip + 64 * jj + u),
                                             (lvp)&st[buf][1][64 * jj], 4, 0, 0);
        __builtin_amdgcn_global_load_lds((gvp)(ip + 449 + u),
                                         (lvp)&st[buf][1][449], 4, 0, 0);
    };  // 18 vmcnt entries per frame

    // ---- prologue: stage the priming frame ----
    if (t0 == 0) {
        #pragma unroll
        for (int j = 0; j < 8; ++j) { st[0][0][u + 64 * j] = 0.f; st[0][1][u + 64 * j] = 0.f; }
        if (u == 0) { st[0][0][512] = 0.f; st[0][1][512] = 0.f; }
    } else {
        stage(t0 - 1, 0);
    }
    asm volatile("s_waitcnt vmcnt(0)" ::: "memory");

    for (int it = 0; it <= FPW; ++it) {
        const int t = t0 - 1 + it;
        const int c = it & 1;

        // ---- wait for frame t's staging (counted: leave newer stores in flight) ----
        if (it >= 2)      { asm volatile("s_waitcnt vmcnt(8)" ::: "memory"); }
        else if (it == 1) { asm volatile("s_waitcnt vmcnt(0)" ::: "memory"); }

        // ---- pack from staged LDS row: z = F*e + twn*h ----
        float zr8[8], zi8[8];
        {
            const float* fr = st[c][0];
            const float* fi = st[c][1];
            #pragma unroll
            for (int j = 0; j < 8; ++j) {
                const int k = u + 64 * j;
                float xr = fr[k], xi = fi[k];
                float rc = fr[512 - k], ic = -fi[512 - k];
                if (k == 0) { xi = 0.f; ic = 0.f; }   // pocketfft c2r: Im ignored
                const float er0 = xr + rc, ei0 = xi + ic;
                const float hr0 = xr - rc, hi0 = xi - ic;
                zr8[j] = F * er0 + (twn[j].x * hr0 - twn[j].y * hi0);
                zi8[j] = F * ei0 + (twn[j].x * hi0 + twn[j].y * hr0);
            }
        }

        // ---- issue next frame's staging; latency hides under the FFT ----
        if (it < FPW) stage(t + 1, c ^ 1);

        // ---- stage A: IDFT8 over the 64s digit, twiddle w64^(k1*m0) ----
        idft8(zr8, zi8);
        {
            float tr = wA.x, ti = wA.y;
            #pragma unroll
            for (int m0 = 1; m0 < 8; ++m0) {
                cmul(zr8[m0], zi8[m0], tr, ti);
                cmul(tr, ti, wA.x, wA.y);
            }
        }
        // ---- exchange 1 (wave-internal, XOR swizzle, no barrier) ----
        #pragma unroll
        for (int m0 = 0; m0 < 8; ++m0)
            ex2[64 * m0 + 8 * ((k1 ^ m0) & 7) + k2] = make_float2(zr8[m0], zi8[m0]);
        #pragma unroll
        for (int kk = 0; kk < 8; ++kk) {
            const float2 v = ex2[64 * k1 + 8 * ((kk ^ k1) & 7) + k2];
            zr8[kk] = v.x; zi8[kk] = v.y;
        }

        // ---- stage B: IDFT8 over the 8s digit, twiddle w512^(k2*(m0B+8*m1)) ----
        idft8(zr8, zi8);
        {
            float tr = wB0.x, ti = wB0.y;
            #pragma unroll
            for (int m1 = 0; m1 < 8; ++m1) {
                cmul(zr8[m1], zi8[m1], tr, ti);
                cmul(tr, ti, wBs.x, wBs.y);
            }
        }
        // ---- exchange 2 (wave-internal) ----
        #pragma unroll
        for (int m1 = 0; m1 < 8; ++m1)
            ex2[64 * k2 + 8 * ((m1 ^ k2) & 7) + k1] = make_float2(zr8[m1], zi8[m1]);
        #pragma unroll
        for (int kk = 0; kk < 8; ++kk) {
            const float2 v = ex2[64 * kk + 8 * ((k1 ^ kk) & 7) + k2];
            zr8[kk] = v.x; zi8[kk] = v.y;
        }

        // ---- stage C: IDFT8 over the 1s digit -> z[u + 64*m2] ----
        idft8(zr8, zi8);

        // ---- overlap-add, carry in registers ----
        if (it >= 1) {
            float2* orow = (float2*)(out + ((size_t)b * NROWS + (size_t)t) * 512);
            #pragma unroll
            for (int m = 0; m < 4; ++m)
                orow[u + 64 * m] = make_float2(zr8[m] + cc[m].x, zi8[m] + cc[m].y);
        }
        #pragma unroll
        for (int m = 0; m < 4; ++m) cc[m] = make_float2(zr8[m + 4], zi8[m + 4]);
    }
}

extern "C" void kernel_launch(void* const* d_in, const int* in_sizes, int n_in,
                              void* d_out, int out_size, void* d_ws, size_t ws_size,
                              hipStream_t stream) {
    const float* re = (const float*)d_in[0];
    const float* im = (const float*)d_in[1];
    float* out = (float*)d_out;
    dim3 grid(CHAINS_PER_BATCH, BATCH);
    istft_kernel<<<grid, 64, 0, stream>>>(re, im, out);
}